// Round 1
// baseline (1369.580 us; speedup 1.0000x reference)
//
#include <hip/hip_runtime.h>
#include <hip/hip_bf16.h>

#define LL 24
#define NN 16384
#define HH 128
#define KP 288           // padded K: 16 op + 56 attr + 32 fd + 32 od + 24 zero + 128 gh
#define LN (LL*NN)

typedef __bf16 bf16;
typedef __attribute__((ext_vector_type(8))) __bf16 bf16x8;
typedef __attribute__((ext_vector_type(4))) __bf16 bf16x4;
typedef __attribute__((ext_vector_type(2))) __bf16 bf16x2;
typedef __attribute__((ext_vector_type(4))) float f32x4;

__device__ __forceinline__ float sigm(float x){ return 1.f/(1.f+__expf(-x)); }
__device__ __forceinline__ float tanhfast(float x){
    float e = __expf(-2.f*fabsf(x));
    float t = (1.f-e)/(1.f+e);
    return x >= 0.f ? t : -t;
}
__device__ __forceinline__ void gld16(const void* g, void* l){
    __builtin_amdgcn_global_load_lds(
        (const __attribute__((address_space(1))) void*)g,
        (__attribute__((address_space(3))) void*)l, 16, 0, 0);
}

// ---------------------------------------------------------------------------
// act = leaky(X @ W.T + b) -> bf16, plus f32 per-channel sum/sumsq for BN.
// Rewritten: 192-row tiles, thread = 6 rows x 4 channels, k-quad float4 LDS
// reads (6 ds_read_b128 per 96 FMAs), W streamed from global (L1-resident).
// DP=84 (D=74): row stride 504 dwords -> 4 distinct 4-bank windows x2 = free.
// ---------------------------------------------------------------------------
template<int D, int DP, int NQ, int TILES>
__global__ __launch_bounds__(256) void act_kernel(
    const float* __restrict__ X, const float* __restrict__ W,
    const float* __restrict__ bias, bf16* __restrict__ act,
    float* __restrict__ sums)
{
    __shared__ float xs[192*DP];
    const int tid = threadIdx.x;
    const int cg  = tid & 7;          // channel group: channels cg*4 .. cg*4+3
    const int rg  = tid >> 3;         // row group: rows rg*6 .. rg*6+5
    const int rbase = rg*6;

    float bc[4];
    #pragma unroll
    for (int c=0;c<4;++c) bc[c] = bias[cg*4+c];

    float s[4] = {0,0,0,0}, qq[4] = {0,0,0,0};

    for (int tile = blockIdx.x; tile < TILES; tile += gridDim.x) {
        __syncthreads();
        const float* Xt = X + (size_t)tile * (192*D);
        for (int i = tid; i < 192*D; i += 256) {
            int r = i / D, c = i - r*D;
            xs[r*DP + c] = Xt[i];
        }
        if constexpr (4*NQ > D) {
            constexpr int PADW = 4*NQ - D;
            for (int i = tid; i < 192*PADW; i += 256) {
                int r = i / PADW, c = i - r*PADW;
                xs[r*DP + D + c] = 0.f;
            }
        }
        __syncthreads();

        float a[6][4];
        #pragma unroll
        for (int i=0;i<6;++i)
            #pragma unroll
            for (int c=0;c<4;++c) a[i][c] = 0.f;

        #pragma unroll 2
        for (int q = 0; q < NQ; ++q) {
            float4 wv[4];
            #pragma unroll
            for (int c = 0; c < 4; ++c) {
                const float* wp = W + (cg*4 + c)*D + q*4;
                if constexpr (D % 4 == 0) {
                    wv[c] = *(const float4*)wp;
                } else {
                    if ((4*NQ > D) && (q == NQ-1)) {     // tail: 2 valid k
                        float2 lo = *(const float2*)wp;
                        wv[c] = make_float4(lo.x, lo.y, 0.f, 0.f);
                    } else {
                        float2 lo = *(const float2*)wp;
                        float2 hi = *(const float2*)(wp+2);
                        wv[c] = make_float4(lo.x, lo.y, hi.x, hi.y);
                    }
                }
            }
            #pragma unroll
            for (int i = 0; i < 6; ++i) {
                float4 xv = *(const float4*)&xs[(rbase+i)*DP + q*4];
                #pragma unroll
                for (int c = 0; c < 4; ++c) {
                    a[i][c] = fmaf(xv.x, wv[c].x, a[i][c]);
                    a[i][c] = fmaf(xv.y, wv[c].y, a[i][c]);
                    a[i][c] = fmaf(xv.z, wv[c].z, a[i][c]);
                    a[i][c] = fmaf(xv.w, wv[c].w, a[i][c]);
                }
            }
        }

        #pragma unroll
        for (int i = 0; i < 6; ++i) {
            bf16x4 pk;
            #pragma unroll
            for (int c = 0; c < 4; ++c) {
                float v = a[i][c] + bc[c];
                v = v > 0.f ? v : 0.01f*v;
                pk[c] = (bf16)v;
                s[c] += v; qq[c] += v*v;
            }
            *(bf16x4*)&act[((size_t)tile*192 + rbase + i)*32 + cg*4] = pk;
        }
    }

    // block reduction of per-channel sum / sumsq, then one atomic per slot
    __syncthreads();
    float* red = xs;                        // reuse LDS: 256*8 = 2048 floats
    #pragma unroll
    for (int c=0;c<4;++c){ red[tid*8 + c*2] = s[c]; red[tid*8 + c*2 + 1] = qq[c]; }
    __syncthreads();
    if (tid < 64) {
        const int ch = tid >> 1, v = tid & 1;     // ch 0..31, v: 0=sum 1=sumsq
        const int cgr = ch >> 2, cl = ch & 3;
        float t = 0.f;
        for (int r = 0; r < 32; ++r)
            t += red[(r*8 + cgr)*8 + cl*2 + v];
        atomicAdd(&sums[v*32 + ch], t);
    }
}

// ---------------------------------------------------------------------------
// Wtb[n'][k] bf16, gate-interleaved column permutation:
// n' = group*64 + gate*16 + c16  ->  orig j = gate*128 + group*16 + c16
// k: [0,136) Wih, [136,160) zero, [160,288) Whh.  b4p[n'] = bih[j]+bhh[j].
// ---------------------------------------------------------------------------
__global__ void prep_wtb(const float* __restrict__ Wih, const float* __restrict__ Whh,
                         const float* __restrict__ bih, const float* __restrict__ bhh,
                         bf16* __restrict__ Wtb, float* __restrict__ b4p)
{
    const int np = blockIdx.x;
    const int k  = threadIdx.x;
    const int gate = (np>>4)&3;
    const int j = gate*128 + (np>>6)*16 + (np&15);
    if (k < KP) {
        float v = 0.f;
        if (k < 136)      v = Wih[(long)j*136 + k];
        else if (k >= 160) v = Whh[(long)j*128 + (k-160)];
        Wtb[(long)np*KP + k] = (bf16)v;
    }
    if (k == 0) b4p[np] = bih[j] + bhh[j];
}

// ---------------------------------------------------------------------------
// BN scale/shift + collapse W2@W1 head.
// ---------------------------------------------------------------------------
__global__ void prep_stats(const float* __restrict__ stats,
    const float* __restrict__ g1, const float* __restrict__ beta1,
    const float* __restrict__ g2, const float* __restrict__ beta2,
    const float* __restrict__ W1, const float* __restrict__ b1,
    const float* __restrict__ W2, const float* __restrict__ b2,
    float* __restrict__ ss, float* __restrict__ wvb)
{
    const int t = threadIdx.x;
    const float inv = 1.f/(float)LN;
    if (t < 32) {
        float mean = stats[t]*inv;
        float var  = stats[32+t]*inv - mean*mean;
        float sc = g1[t]/sqrtf(var + 1e-5f);
        ss[t] = sc; ss[32+t] = beta1[t] - mean*sc;
    } else if (t < 64) {
        int c = t - 32;
        float mean = stats[64+c]*inv;
        float var  = stats[96+c]*inv - mean*mean;
        float sc = g2[c]/sqrtf(var + 1e-5f);
        ss[64+c] = sc; ss[96+c] = beta2[c] - mean*sc;
    }
    float s = 0.f;
    for (int a=0;a<20;++a) s += W2[a]*W1[a*HH + t];
    wvb[t] = s;
    if (t == 0) {
        float sb = 0.f;
        for (int a=0;a<20;++a) sb += W2[a]*b1[a];
        wvb[128] = sb + b2[0];
    }
}

// ---------------------------------------------------------------------------
// Build A[n][k] bf16 (row stride 288): [op16|attr56|fd32|od32|0*24|gh128]
// 32 rows/block; thread handles one 8-elem chunk per iter (all section
// boundaries are multiples of 8).
// ---------------------------------------------------------------------------
__global__ __launch_bounds__(256) void build_a(
    const float* __restrict__ op, const float* __restrict__ attr,
    const bf16* __restrict__ actf, const bf16* __restrict__ acto,
    const int* __restrict__ map, const float* __restrict__ ss,
    const bf16* __restrict__ h_prev, bf16* __restrict__ A,
    int l, int first)
{
    const int n0 = blockIdx.x * 32;
    const long lbase = (long)l * NN;
    for (int i = threadIdx.x; i < 32*36; i += 256) {
        const int r = i / 36, c = i - r*36;
        const long n = n0 + r;
        const long e = lbase + n;
        const int k0 = c*8;
        bf16x8 out;
        if (c < 9) {                                   // op (c<2) or attr
            const float* src = (c < 2) ? (op + e*16 + k0) : (attr + e*56 + (k0-16));
            float4 f0 = *(const float4*)src;
            float4 f1 = *(const float4*)(src+4);
            out[0]=(bf16)f0.x; out[1]=(bf16)f0.y; out[2]=(bf16)f0.z; out[3]=(bf16)f0.w;
            out[4]=(bf16)f1.x; out[5]=(bf16)f1.y; out[6]=(bf16)f1.z; out[7]=(bf16)f1.w;
        } else if (c < 17) {                           // fd / od with BN fold
            const int ch = (c < 13) ? (k0-72) : (k0-104);
            const bf16* src = (c < 13) ? (actf + e*32 + ch) : (acto + e*32 + ch);
            const float* s = ss + ((c < 13) ? 0 : 64);
            bf16x8 v = *(const bf16x8*)src;
            #pragma unroll
            for (int j=0;j<8;++j)
                out[j] = (bf16)fmaf((float)v[j], s[ch+j], s[32+ch+j]);
        } else if (c < 20) {                           // zero pad
            #pragma unroll
            for (int j=0;j<8;++j) out[j] = (bf16)0.f;
        } else {                                       // gh gather
            const int jj = k0 - 160;
            float g[8] = {0,0,0,0,0,0,0,0};
            if (!first) {
                int2 mp = *(const int2*)&map[e*2];
                if (mp.x) { bf16x8 v = *(const bf16x8*)&h_prev[(long)(mp.x-1)*HH + jj];
                    #pragma unroll
                    for (int j=0;j<8;++j) g[j] += (float)v[j]; }
                if (mp.y) { bf16x8 v = *(const bf16x8*)&h_prev[(long)(mp.y-1)*HH + jj];
                    #pragma unroll
                    for (int j=0;j<8;++j) g[j] += (float)v[j]; }
            }
            #pragma unroll
            for (int j=0;j<8;++j) out[j] = (bf16)(0.5f*g[j]);
        }
        *(bf16x8*)&A[n*KP + k0] = out;
    }
}

// ---------------------------------------------------------------------------
// MFMA GEMM + fused LSTM cell. 128x128 tile, BK=32, 9 k-steps.
// 4 waves in 2x2; wave tile 64x64 = 4x4 of 16x16x32 bf16 MFMA.
// Gate-interleaved B => wave's 4 n-tiles = gates i,f,g,o of same 16 cells.
// LDS slot swizzle q^((row>>1)&3) keeps frag ds_read_b128 conflict-free and
// stays compatible with global_load_lds's base+lane*16 destination rule.
// ---------------------------------------------------------------------------
__global__ __launch_bounds__(256) void lstm_gemm(
    const bf16* __restrict__ A, const bf16* __restrict__ Wtb,
    const float* __restrict__ b4p, const int* __restrict__ map,
    const float* __restrict__ c_prev, float* __restrict__ c_next,
    bf16* __restrict__ h_next, int l, int first)
{
    __shared__ bf16 As[128*32];
    __shared__ bf16 Bs[128*32];
    const int tid  = threadIdx.x;
    const int bm   = blockIdx.x;          // 0..127 (fast dim -> siblings share XCD)
    const int bn   = blockIdx.y;          // 0..3
    const int m0   = bm*128, n0p = bn*128;
    const int lane = tid & 63, w = tid >> 6;
    const int wr   = w >> 1,  wc = w & 1;

    f32x4 acc[4][4];
    #pragma unroll
    for (int ni=0; ni<4; ++ni){
        float b = b4p[n0p + wc*64 + ni*16 + (lane&15)];
        #pragma unroll
        for (int mi=0; mi<4; ++mi) acc[mi][ni] = (f32x4){b,b,b,b};
    }

    const bf16* Ab = A   + (size_t)m0*KP;
    const bf16* Bb = Wtb + (size_t)n0p*KP;
    const int lrr = lane >> 2;
    const int qs  = lane & 3;

    for (int kk=0; kk<9; ++kk){
        __syncthreads();
        #pragma unroll
        for (int hh=0; hh<2; ++hh){
            const int lr = w*32 + hh*16 + lrr;
            const int q  = qs ^ ((lr>>1)&3);
            const size_t go = (size_t)lr*KP + kk*32 + q*8;
            gld16(Ab + go, &As[(w*32 + hh*16)*32]);
            gld16(Bb + go, &Bs[(w*32 + hh*16)*32]);
        }
        __syncthreads();
        bf16x8 af[4], bfr[4];
        #pragma unroll
        for (int t4=0; t4<4; ++t4){
            const int am = wr*64 + t4*16 + (lane&15);
            af[t4] = *(const bf16x8*)&As[am*32 + (((lane>>4) ^ ((am>>1)&3))<<3)];
            const int bn_ = wc*64 + t4*16 + (lane&15);
            bfr[t4] = *(const bf16x8*)&Bs[bn_*32 + (((lane>>4) ^ ((bn_>>1)&3))<<3)];
        }
        #pragma unroll
        for (int mi=0; mi<4; ++mi)
            #pragma unroll
            for (int ni=0; ni<4; ++ni)
                acc[mi][ni] = __builtin_amdgcn_mfma_f32_16x16x32_bf16(
                    af[mi], bfr[ni], acc[mi][ni], 0, 0, 0);
    }

    // fused LSTM cell epilogue: gates i,f,g,o are acc[mi][0..3], same lane
    const long lbase = (long)l * NN;
    const int cell = bn*32 + wc*16 + (lane&15);
    #pragma unroll
    for (int mi=0; mi<4; ++mi){
        const int rbase = m0 + wr*64 + mi*16 + (lane>>4)*4;
        #pragma unroll
        for (int reg=0; reg<4; ++reg){
            const int n = rbase + reg;
            float gc = 0.f;
            if (!first){
                int2 mp = *(const int2*)&map[(lbase+n)*2];
                if (mp.x) gc += c_prev[(long)(mp.x-1)*HH + cell];
                if (mp.y) gc += c_prev[(long)(mp.y-1)*HH + cell];
                gc *= 0.5f;
            }
            float cn = sigm(acc[mi][1][reg])*gc
                     + sigm(acc[mi][0][reg])*tanhfast(acc[mi][2][reg]);
            float hn = sigm(acc[mi][3][reg])*tanhfast(cn);
            c_next[(long)n*HH + cell] = cn;
            h_next[(long)n*HH + cell] = (bf16)hn;
        }
    }
}

// ---------------------------------------------------------------------------
// out[n] = sigmoid(h[n] . wv + wb); one wave per row.
// ---------------------------------------------------------------------------
__global__ __launch_bounds__(256) void final_k(
    const bf16* __restrict__ h, const float* __restrict__ wvb,
    float* __restrict__ out, int rows)
{
    int gt = blockIdx.x*256 + threadIdx.x;
    int row = gt >> 6;
    int lane = gt & 63;
    if (row >= rows) return;
    float v = fmaf((float)h[(long)row*HH + lane], wvb[lane],
                   (float)h[(long)row*HH + 64 + lane] * wvb[64+lane]);
    #pragma unroll
    for (int off=32; off>0; off>>=1) v += __shfl_down(v, off);
    if (lane == 0) out[row] = sigm(v + wvb[128]);
}

extern "C" void kernel_launch(void* const* d_in, const int* in_sizes, int n_in,
                              void* d_out, int out_size, void* d_ws, size_t ws_size,
                              hipStream_t stream)
{
    const float* op      = (const float*)d_in[0];
    const float* attr    = (const float*)d_in[1];
    const float* filt    = (const float*)d_in[2];
    const float* outp    = (const float*)d_in[3];
    const int*   mapping = (const int*)d_in[4];
    const float* Wf  = (const float*)d_in[6];
    const float* bf_ = (const float*)d_in[7];
    const float* Wo  = (const float*)d_in[8];
    const float* bo  = (const float*)d_in[9];
    const float* g1  = (const float*)d_in[10];
    const float* be1 = (const float*)d_in[11];
    const float* g2  = (const float*)d_in[12];
    const float* be2 = (const float*)d_in[13];
    const float* Wih = (const float*)d_in[14];
    const float* Whh = (const float*)d_in[15];
    const float* bih = (const float*)d_in[16];
    const float* bhh = (const float*)d_in[17];
    const float* W1  = (const float*)d_in[18];
    const float* b1  = (const float*)d_in[19];
    const float* W2  = (const float*)d_in[20];
    const float* b2  = (const float*)d_in[21];

    char* p = (char*)d_ws;
    auto alloc = [&](size_t bytes){ char* r = p; p += (bytes + 255) & ~255ull; return r; };
    bf16* actf = (bf16*)alloc((size_t)LN*32*2);
    bf16* acto = (bf16*)alloc((size_t)LN*32*2);
    bf16* h0   = (bf16*)alloc((size_t)NN*HH*2);
    bf16* h1   = (bf16*)alloc((size_t)NN*HH*2);
    float* c0  = (float*)alloc((size_t)NN*HH*4);
    float* c1  = (float*)alloc((size_t)NN*HH*4);
    bf16* Abuf = (bf16*)alloc((size_t)NN*KP*2);
    bf16* Wtb  = (bf16*)alloc((size_t)512*KP*2);
    float* b4p = (float*)alloc(512*4);
    float* stats=(float*)alloc(128*4);
    float* ssb = (float*)alloc(128*4);
    float* wvb = (float*)alloc(132*4);

    hipMemsetAsync(stats, 0, 128*sizeof(float), stream);
    // D=74: 2048 tiles of 192 rows, grid 512 (2 blocks/CU, LDS-bound), 4 tiles each
    act_kernel<74, 84, 19, 2048><<<512, 256, 0, stream>>>(filt, Wf, bf_, actf, stats);
    // D=32: lighter LDS (27 KB) -> grid 1024 (4 blocks/CU), 2 tiles each
    act_kernel<32, 36,  8, 2048><<<1024, 256, 0, stream>>>(outp, Wo, bo, acto, stats+64);
    prep_wtb<<<512, 320, 0, stream>>>(Wih, Whh, bih, bhh, Wtb, b4p);
    prep_stats<<<1, 128, 0, stream>>>(stats, g1, be1, g2, be2, W1, b1, W2, b2, ssb, wvb);

    bf16*  hb[2] = {h0, h1};
    float* cb[2] = {c0, c1};
    for (int t = 0; t < LL; ++t) {
        const int l = (LL-1) - t;
        const int first = (t == 0);
        build_a<<<NN/32, 256, 0, stream>>>(op, attr, actf, acto, mapping, ssb,
                                           hb[t&1], Abuf, l, first);
        lstm_gemm<<<dim3(128,4), 256, 0, stream>>>(Abuf, Wtb, b4p, mapping,
            cb[t&1], cb[(t+1)&1], hb[(t+1)&1], l, first);
    }
    final_k<<<(out_size*64 + 255)/256, 256, 0, stream>>>(hb[0], wvb, (float*)d_out, out_size);
}

// Round 2
// 1321.028 us; speedup vs baseline: 1.0368x; 1.0368x over previous
//
#include <hip/hip_runtime.h>
#include <hip/hip_bf16.h>

#define LL 24
#define NN 16384
#define HH 128
#define KP 288           // padded K: 16 op + 56 attr + 32 fd + 32 od + 24 zero + 128 gh
#define LN (LL*NN)

typedef __bf16 bf16;
typedef __attribute__((ext_vector_type(8))) __bf16 bf16x8;
typedef __attribute__((ext_vector_type(4))) __bf16 bf16x4;
typedef __attribute__((ext_vector_type(2))) __bf16 bf16x2;
typedef __attribute__((ext_vector_type(4))) float f32x4;

__device__ __forceinline__ float sigm(float x){ return 1.f/(1.f+__expf(-x)); }
__device__ __forceinline__ float tanhfast(float x){
    float e = __expf(-2.f*fabsf(x));
    float t = (1.f-e)/(1.f+e);
    return x >= 0.f ? t : -t;
}
__device__ __forceinline__ void gld16(const void* g, void* l){
    __builtin_amdgcn_global_load_lds(
        (const __attribute__((address_space(1))) void*)g,
        (__attribute__((address_space(3))) void*)l, 16, 0, 0);
}

// ---------------------------------------------------------------------------
// W split prep: Wsp = [ WH | WL ], each [KQ][32 ch][8 k] bf16.
// hi = bf16(w), lo = bf16(w - hi);  k >= D zero-padded.
// ---------------------------------------------------------------------------
template<int D, int KQ>
__global__ void prep_wsplit(const float* __restrict__ W, bf16* __restrict__ Wsp)
{
    for (int idx = threadIdx.x; idx < KQ*256; idx += blockDim.x) {
        const int j   = idx & 7;
        const int col = (idx >> 3) & 31;
        const int kq  = idx >> 8;
        const int k   = kq*8 + j;
        float v = (k < D) ? W[col*D + k] : 0.f;
        bf16 h = (bf16)v;
        Wsp[idx]          = h;
        Wsp[KQ*256 + idx] = (bf16)(v - (float)h);
    }
}

// ---------------------------------------------------------------------------
// act = leaky(X @ W.T + b) via split-bf16 MFMA (error ~2^-16, << bf16 store
// rounding).  Swapped operands: A=W (m=channel), B=X (n=row) so C gives 4
// ADJACENT channels per lane -> packed 8B stores.
// LDS: XH/XL [KQ][row] 16B units, kq stride 130 units (conflict-free phases
// for both staging ds_write_b128 and fragment ds_read_b128).
// Block: 256 thr / 4 waves, 128-row tile, wave = 32 rows (2 row-tiles).
// ---------------------------------------------------------------------------
template<int D, int KQ, int NQK>
__global__ __launch_bounds__(256) void act_mfma(
    const float* __restrict__ X, const bf16* __restrict__ Wsp,
    const float* __restrict__ bias, bf16* __restrict__ act,
    float* __restrict__ sums)
{
    constexpr int KSTEPS = KQ/4;
    constexpr int TILES  = LN/128;
    __shared__ __align__(16) bf16 XH[KQ*130*8];
    __shared__ __align__(16) bf16 XL[KQ*130*8];
    __shared__ float red[64];
    const int tid  = threadIdx.x;
    const int lane = tid & 63, w = tid >> 6;
    const int l15  = lane & 15, l4 = lane >> 4;

    if (tid < 64) red[tid] = 0.f;

    // zero the wholly-padded quads once (never rewritten by staging)
    if constexpr (KQ > NQK) {
        for (int s = tid; s < (KQ-NQK)*128; s += 256) {
            const int kq = NQK + (s >> 7), r = s & 127;
            bf16x8 z;
            #pragma unroll
            for (int j=0;j<8;++j) z[j] = (bf16)0.f;
            *(bf16x8*)&XH[(kq*130 + r)*8] = z;
            *(bf16x8*)&XL[(kq*130 + r)*8] = z;
        }
    }

    // W fragments in registers for the whole kernel
    bf16x8 wh[KSTEPS][2], wl[KSTEPS][2];
    #pragma unroll
    for (int ks=0; ks<KSTEPS; ++ks)
        #pragma unroll
        for (int cht=0; cht<2; ++cht) {
            const int idx = ((ks*4 + l4)*32 + cht*16 + l15)*8;
            wh[ks][cht] = *(const bf16x8*)&Wsp[idx];
            wl[ks][cht] = *(const bf16x8*)&Wsp[KQ*256 + idx];
        }
    float4 bb[2];
    #pragma unroll
    for (int cht=0; cht<2; ++cht) bb[cht] = *(const float4*)&bias[cht*16 + l4*4];

    float sst[2][4], ssq[2][4];
    #pragma unroll
    for (int c=0;c<2;++c)
        #pragma unroll
        for (int r=0;r<4;++r){ sst[c][r]=0.f; ssq[c][r]=0.f; }

    const int rowb = w*32;
    for (int tile = blockIdx.x; tile < TILES; tile += gridDim.x) {
        __syncthreads();
        const float* Xt = X + (size_t)tile*128*D;
        #pragma unroll
        for (int it = 0; it < (128*NQK)/256; ++it) {
            const int t = it*256 + tid;
            const int r = t / NQK, q = t - r*NQK;
            const float* src = Xt + (size_t)r*D + q*8;
            float xv[8];
            if constexpr (D % 8 != 0) {
                if (q == NQK-1) {
                    #pragma unroll
                    for (int j=0;j<8;++j) xv[j] = (j < D-(NQK-1)*8) ? src[j] : 0.f;
                } else {
                    float2 p0 = *(const float2*)(src);
                    float2 p1 = *(const float2*)(src+2);
                    float2 p2 = *(const float2*)(src+4);
                    float2 p3 = *(const float2*)(src+6);
                    xv[0]=p0.x; xv[1]=p0.y; xv[2]=p1.x; xv[3]=p1.y;
                    xv[4]=p2.x; xv[5]=p2.y; xv[6]=p3.x; xv[7]=p3.y;
                }
            } else {
                float4 f0 = *(const float4*)src;
                float4 f1 = *(const float4*)(src+4);
                xv[0]=f0.x; xv[1]=f0.y; xv[2]=f0.z; xv[3]=f0.w;
                xv[4]=f1.x; xv[5]=f1.y; xv[6]=f1.z; xv[7]=f1.w;
            }
            bf16x8 h8, l8;
            #pragma unroll
            for (int j=0;j<8;++j){
                float x = xv[j];
                bf16 hh = (bf16)x;
                h8[j] = hh;
                l8[j] = (bf16)(x - (float)hh);
            }
            const int slot = (q*130 + r)*8;
            *(bf16x8*)&XH[slot] = h8;
            *(bf16x8*)&XL[slot] = l8;
        }
        __syncthreads();

        f32x4 acc[2][2];
        #pragma unroll
        for (int cht=0; cht<2; ++cht)
            #pragma unroll
            for (int rt=0; rt<2; ++rt)
                acc[cht][rt] = (f32x4){bb[cht].x, bb[cht].y, bb[cht].z, bb[cht].w};

        #pragma unroll
        for (int ks=0; ks<KSTEPS; ++ks) {
            bf16x8 xh[2], xl[2];
            #pragma unroll
            for (int rt=0; rt<2; ++rt) {
                const int slot = ((ks*4 + l4)*130 + rowb + rt*16 + l15)*8;
                xh[rt] = *(const bf16x8*)&XH[slot];
                xl[rt] = *(const bf16x8*)&XL[slot];
            }
            #pragma unroll
            for (int cht=0; cht<2; ++cht)
                #pragma unroll
                for (int rt=0; rt<2; ++rt) {
                    acc[cht][rt] = __builtin_amdgcn_mfma_f32_16x16x32_bf16(
                        wh[ks][cht], xh[rt], acc[cht][rt], 0,0,0);
                    acc[cht][rt] = __builtin_amdgcn_mfma_f32_16x16x32_bf16(
                        wl[ks][cht], xh[rt], acc[cht][rt], 0,0,0);
                    acc[cht][rt] = __builtin_amdgcn_mfma_f32_16x16x32_bf16(
                        wh[ks][cht], xl[rt], acc[cht][rt], 0,0,0);
                }
        }

        #pragma unroll
        for (int cht=0; cht<2; ++cht)
            #pragma unroll
            for (int rt=0; rt<2; ++rt) {
                bf16x4 pk;
                #pragma unroll
                for (int reg=0; reg<4; ++reg) {
                    float u = acc[cht][rt][reg];
                    u = u > 0.f ? u : 0.01f*u;
                    pk[reg] = (bf16)u;
                    sst[cht][reg] += u;
                    ssq[cht][reg] += u*u;
                }
                const long row = (long)tile*128 + rowb + rt*16 + l15;
                *(bf16x4*)&act[row*32 + cht*16 + l4*4] = pk;
            }
    }

    __syncthreads();
    #pragma unroll
    for (int cht=0; cht<2; ++cht)
        #pragma unroll
        for (int reg=0; reg<4; ++reg) {
            const int ch = cht*16 + l4*4 + reg;
            atomicAdd(&red[ch],      sst[cht][reg]);
            atomicAdd(&red[32+ch],   ssq[cht][reg]);
        }
    __syncthreads();
    if (tid < 64) atomicAdd(&sums[tid], red[tid]);
}

// ---------------------------------------------------------------------------
// Wtb[n'][k] bf16, gate-interleaved column permutation:
// n' = group*64 + gate*16 + c16  ->  orig j = gate*128 + group*16 + c16
// k: [0,136) Wih, [136,160) zero, [160,288) Whh.  b4p[n'] = bih[j]+bhh[j].
// ---------------------------------------------------------------------------
__global__ void prep_wtb(const float* __restrict__ Wih, const float* __restrict__ Whh,
                         const float* __restrict__ bih, const float* __restrict__ bhh,
                         bf16* __restrict__ Wtb, float* __restrict__ b4p)
{
    const int np = blockIdx.x;
    const int k  = threadIdx.x;
    const int gate = (np>>4)&3;
    const int j = gate*128 + (np>>6)*16 + (np&15);
    if (k < KP) {
        float v = 0.f;
        if (k < 136)      v = Wih[(long)j*136 + k];
        else if (k >= 160) v = Whh[(long)j*128 + (k-160)];
        Wtb[(long)np*KP + k] = (bf16)v;
    }
    if (k == 0) b4p[np] = bih[j] + bhh[j];
}

// ---------------------------------------------------------------------------
// BN scale/shift + collapse W2@W1 head.
// ---------------------------------------------------------------------------
__global__ void prep_stats(const float* __restrict__ stats,
    const float* __restrict__ g1, const float* __restrict__ beta1,
    const float* __restrict__ g2, const float* __restrict__ beta2,
    const float* __restrict__ W1, const float* __restrict__ b1,
    const float* __restrict__ W2, const float* __restrict__ b2,
    float* __restrict__ ss, float* __restrict__ wvb)
{
    const int t = threadIdx.x;
    const float inv = 1.f/(float)LN;
    if (t < 32) {
        float mean = stats[t]*inv;
        float var  = stats[32+t]*inv - mean*mean;
        float sc = g1[t]/sqrtf(var + 1e-5f);
        ss[t] = sc; ss[32+t] = beta1[t] - mean*sc;
    } else if (t < 64) {
        int c = t - 32;
        float mean = stats[64+c]*inv;
        float var  = stats[96+c]*inv - mean*mean;
        float sc = g2[c]/sqrtf(var + 1e-5f);
        ss[64+c] = sc; ss[96+c] = beta2[c] - mean*sc;
    }
    float s = 0.f;
    for (int a=0;a<20;++a) s += W2[a]*W1[a*HH + t];
    wvb[t] = s;
    if (t == 0) {
        float sb = 0.f;
        for (int a=0;a<20;++a) sb += W2[a]*b1[a];
        wvb[128] = sb + b2[0];
    }
}

// ---------------------------------------------------------------------------
// Build A[n][k] bf16 (row stride 288): [op16|attr56|fd32|od32|0*24|gh128]
// 32 rows/block; thread handles one 8-elem chunk per iter (all section
// boundaries are multiples of 8).
// ---------------------------------------------------------------------------
__global__ __launch_bounds__(256) void build_a(
    const float* __restrict__ op, const float* __restrict__ attr,
    const bf16* __restrict__ actf, const bf16* __restrict__ acto,
    const int* __restrict__ map, const float* __restrict__ ss,
    const bf16* __restrict__ h_prev, bf16* __restrict__ A,
    int l, int first)
{
    const int n0 = blockIdx.x * 32;
    const long lbase = (long)l * NN;
    for (int i = threadIdx.x; i < 32*36; i += 256) {
        const int r = i / 36, c = i - r*36;
        const long n = n0 + r;
        const long e = lbase + n;
        const int k0 = c*8;
        bf16x8 out;
        if (c < 9) {                                   // op (c<2) or attr
            const float* src = (c < 2) ? (op + e*16 + k0) : (attr + e*56 + (k0-16));
            float4 f0 = *(const float4*)src;
            float4 f1 = *(const float4*)(src+4);
            out[0]=(bf16)f0.x; out[1]=(bf16)f0.y; out[2]=(bf16)f0.z; out[3]=(bf16)f0.w;
            out[4]=(bf16)f1.x; out[5]=(bf16)f1.y; out[6]=(bf16)f1.z; out[7]=(bf16)f1.w;
        } else if (c < 17) {                           // fd / od with BN fold
            const int ch = (c < 13) ? (k0-72) : (k0-104);
            const bf16* src = (c < 13) ? (actf + e*32 + ch) : (acto + e*32 + ch);
            const float* s = ss + ((c < 13) ? 0 : 64);
            bf16x8 v = *(const bf16x8*)src;
            #pragma unroll
            for (int j=0;j<8;++j)
                out[j] = (bf16)fmaf((float)v[j], s[ch+j], s[32+ch+j]);
        } else if (c < 20) {                           // zero pad
            #pragma unroll
            for (int j=0;j<8;++j) out[j] = (bf16)0.f;
        } else {                                       // gh gather
            const int jj = k0 - 160;
            float g[8] = {0,0,0,0,0,0,0,0};
            if (!first) {
                int2 mp = *(const int2*)&map[e*2];
                if (mp.x) { bf16x8 v = *(const bf16x8*)&h_prev[(long)(mp.x-1)*HH + jj];
                    #pragma unroll
                    for (int j=0;j<8;++j) g[j] += (float)v[j]; }
                if (mp.y) { bf16x8 v = *(const bf16x8*)&h_prev[(long)(mp.y-1)*HH + jj];
                    #pragma unroll
                    for (int j=0;j<8;++j) g[j] += (float)v[j]; }
            }
            #pragma unroll
            for (int j=0;j<8;++j) out[j] = (bf16)(0.5f*g[j]);
        }
        *(bf16x8*)&A[n*KP + k0] = out;
    }
}

// ---------------------------------------------------------------------------
// MFMA GEMM + fused LSTM cell. 128x128 tile, BK=32, 9 k-steps.
// 4 waves in 2x2; wave tile 64x64 = 4x4 of 16x16x32 bf16 MFMA.
// Gate-interleaved B => wave's 4 n-tiles = gates i,f,g,o of same 16 cells.
// LDS slot swizzle q^((row>>1)&3) keeps frag ds_read_b128 conflict-free and
// stays compatible with global_load_lds's base+lane*16 destination rule.
// ---------------------------------------------------------------------------
__global__ __launch_bounds__(256) void lstm_gemm(
    const bf16* __restrict__ A, const bf16* __restrict__ Wtb,
    const float* __restrict__ b4p, const int* __restrict__ map,
    const float* __restrict__ c_prev, float* __restrict__ c_next,
    bf16* __restrict__ h_next, int l, int first)
{
    __shared__ bf16 As[128*32];
    __shared__ bf16 Bs[128*32];
    const int tid  = threadIdx.x;
    const int bm   = blockIdx.x;          // 0..127 (fast dim -> siblings share XCD)
    const int bn   = blockIdx.y;          // 0..3
    const int m0   = bm*128, n0p = bn*128;
    const int lane = tid & 63, w = tid >> 6;
    const int wr   = w >> 1,  wc = w & 1;

    f32x4 acc[4][4];
    #pragma unroll
    for (int ni=0; ni<4; ++ni){
        float b = b4p[n0p + wc*64 + ni*16 + (lane&15)];
        #pragma unroll
        for (int mi=0; mi<4; ++mi) acc[mi][ni] = (f32x4){b,b,b,b};
    }

    const bf16* Ab = A   + (size_t)m0*KP;
    const bf16* Bb = Wtb + (size_t)n0p*KP;
    const int lrr = lane >> 2;
    const int qs  = lane & 3;

    for (int kk=0; kk<9; ++kk){
        __syncthreads();
        #pragma unroll
        for (int hh=0; hh<2; ++hh){
            const int lr = w*32 + hh*16 + lrr;
            const int q  = qs ^ ((lr>>1)&3);
            const size_t go = (size_t)lr*KP + kk*32 + q*8;
            gld16(Ab + go, &As[(w*32 + hh*16)*32]);
            gld16(Bb + go, &Bs[(w*32 + hh*16)*32]);
        }
        __syncthreads();
        bf16x8 af[4], bfr[4];
        #pragma unroll
        for (int t4=0; t4<4; ++t4){
            const int am = wr*64 + t4*16 + (lane&15);
            af[t4] = *(const bf16x8*)&As[am*32 + (((lane>>4) ^ ((am>>1)&3))<<3)];
            const int bn_ = wc*64 + t4*16 + (lane&15);
            bfr[t4] = *(const bf16x8*)&Bs[bn_*32 + (((lane>>4) ^ ((bn_>>1)&3))<<3)];
        }
        #pragma unroll
        for (int mi=0; mi<4; ++mi)
            #pragma unroll
            for (int ni=0; ni<4; ++ni)
                acc[mi][ni] = __builtin_amdgcn_mfma_f32_16x16x32_bf16(
                    af[mi], bfr[ni], acc[mi][ni], 0, 0, 0);
    }

    // fused LSTM cell epilogue: gates i,f,g,o are acc[mi][0..3], same lane
    const long lbase = (long)l * NN;
    const int cell = bn*32 + wc*16 + (lane&15);
    #pragma unroll
    for (int mi=0; mi<4; ++mi){
        const int rbase = m0 + wr*64 + mi*16 + (lane>>4)*4;
        #pragma unroll
        for (int reg=0; reg<4; ++reg){
            const int n = rbase + reg;
            float gc = 0.f;
            if (!first){
                int2 mp = *(const int2*)&map[(lbase+n)*2];
                if (mp.x) gc += c_prev[(long)(mp.x-1)*HH + cell];
                if (mp.y) gc += c_prev[(long)(mp.y-1)*HH + cell];
                gc *= 0.5f;
            }
            float cn = sigm(acc[mi][1][reg])*gc
                     + sigm(acc[mi][0][reg])*tanhfast(acc[mi][2][reg]);
            float hn = sigm(acc[mi][3][reg])*tanhfast(cn);
            c_next[(long)n*HH + cell] = cn;
            h_next[(long)n*HH + cell] = (bf16)hn;
        }
    }
}

// ---------------------------------------------------------------------------
// out[n] = sigmoid(h[n] . wv + wb); one wave per row.
// ---------------------------------------------------------------------------
__global__ __launch_bounds__(256) void final_k(
    const bf16* __restrict__ h, const float* __restrict__ wvb,
    float* __restrict__ out, int rows)
{
    int gt = blockIdx.x*256 + threadIdx.x;
    int row = gt >> 6;
    int lane = gt & 63;
    if (row >= rows) return;
    float v = fmaf((float)h[(long)row*HH + lane], wvb[lane],
                   (float)h[(long)row*HH + 64 + lane] * wvb[64+lane]);
    #pragma unroll
    for (int off=32; off>0; off>>=1) v += __shfl_down(v, off);
    if (lane == 0) out[row] = sigm(v + wvb[128]);
}

extern "C" void kernel_launch(void* const* d_in, const int* in_sizes, int n_in,
                              void* d_out, int out_size, void* d_ws, size_t ws_size,
                              hipStream_t stream)
{
    const float* op      = (const float*)d_in[0];
    const float* attr    = (const float*)d_in[1];
    const float* filt    = (const float*)d_in[2];
    const float* outp    = (const float*)d_in[3];
    const int*   mapping = (const int*)d_in[4];
    const float* Wf  = (const float*)d_in[6];
    const float* bf_ = (const float*)d_in[7];
    const float* Wo  = (const float*)d_in[8];
    const float* bo  = (const float*)d_in[9];
    const float* g1  = (const float*)d_in[10];
    const float* be1 = (const float*)d_in[11];
    const float* g2  = (const float*)d_in[12];
    const float* be2 = (const float*)d_in[13];
    const float* Wih = (const float*)d_in[14];
    const float* Whh = (const float*)d_in[15];
    const float* bih = (const float*)d_in[16];
    const float* bhh = (const float*)d_in[17];
    const float* W1  = (const float*)d_in[18];
    const float* b1  = (const float*)d_in[19];
    const float* W2  = (const float*)d_in[20];
    const float* b2  = (const float*)d_in[21];

    char* p = (char*)d_ws;
    auto alloc = [&](size_t bytes){ char* r = p; p += (bytes + 255) & ~255ull; return r; };
    bf16* actf = (bf16*)alloc((size_t)LN*32*2);
    bf16* acto = (bf16*)alloc((size_t)LN*32*2);
    bf16* h0   = (bf16*)alloc((size_t)NN*HH*2);
    bf16* h1   = (bf16*)alloc((size_t)NN*HH*2);
    float* c0  = (float*)alloc((size_t)NN*HH*4);
    float* c1  = (float*)alloc((size_t)NN*HH*4);
    bf16* Abuf = (bf16*)alloc((size_t)NN*KP*2);
    bf16* Wtb  = (bf16*)alloc((size_t)512*KP*2);
    float* b4p = (float*)alloc(512*4);
    float* stats=(float*)alloc(128*4);
    float* ssb = (float*)alloc(128*4);
    float* wvb = (float*)alloc(132*4);
    bf16* wspf = (bf16*)alloc((size_t)12*256*2*2);   // [WH|WL] for Wf, KQ=12
    bf16* wspo = (bf16*)alloc((size_t)4*256*2*2);    // [WH|WL] for Wo, KQ=4

    hipMemsetAsync(stats, 0, 128*sizeof(float), stream);
    prep_wsplit<74,12><<<1, 256, 0, stream>>>(Wf, wspf);
    prep_wsplit<32, 4><<<1, 256, 0, stream>>>(Wo, wspo);
    // D=74: KQ=12 (K pad 96), 10 staged quads; 50KB LDS -> 3 blocks/CU, 4 tiles each
    act_mfma<74,12,10><<<768, 256, 0, stream>>>(filt, wspf, bf_, actf, stats);
    // D=32: KQ=4 (K=32 exact); 17KB LDS; 1536 blocks, 2 tiles each
    act_mfma<32, 4, 4><<<1536, 256, 0, stream>>>(outp, wspo, bo, acto, stats+64);
    prep_wtb<<<512, 320, 0, stream>>>(Wih, Whh, bih, bhh, Wtb, b4p);
    prep_stats<<<1, 128, 0, stream>>>(stats, g1, be1, g2, be2, W1, b1, W2, b2, ssb, wvb);

    bf16*  hb[2] = {h0, h1};
    float* cb[2] = {c0, c1};
    for (int t = 0; t < LL; ++t) {
        const int l = (LL-1) - t;
        const int first = (t == 0);
        build_a<<<NN/32, 256, 0, stream>>>(op, attr, actf, acto, mapping, ssb,
                                           hb[t&1], Abuf, l, first);
        lstm_gemm<<<dim3(128,4), 256, 0, stream>>>(Abuf, Wtb, b4p, mapping,
            cb[t&1], cb[(t+1)&1], hb[(t+1)&1], l, first);
    }
    final_k<<<(out_size*64 + 255)/256, 256, 0, stream>>>(hb[0], wvb, (float*)d_out, out_size);
}